// Round 19
// baseline (413.010 us; speedup 1.0000x reference)
//
#include <hip/hip_runtime.h>
#include <cstdint>

// SS2D forward. Round 19 = R18 with k_scan residency unblocked on BOTH axes
// while keeping the proven win32 structure:
//  - dds packed bf16x2 (uint): LDS 40.9KB -> 24KB (6 blocks/CU cap)
//  - 12 chunks (OWN=192, WARM=128): grid 864 -> 1152 (4.5 blocks/CU avg)
//  - launch_bounds(256,4) kept (no VGPR pressure; spill tripwire = FETCH)
// B=8 C=192 H=W=48 L=2304 D_EXP=D_INNER=384 K=4 N=16 R=12

static constexpr int L = 2304;

typedef __attribute__((ext_vector_type(8))) short short8;
typedef __attribute__((ext_vector_type(8))) unsigned short ushort8;
typedef __attribute__((ext_vector_type(4))) float f32x4;

__device__ __forceinline__ float gelu_f(float x) {
  return 0.5f * x * (1.0f + erff(x * 0.70710678118654752440f));
}

__device__ __forceinline__ unsigned short bf16r(float f) {
  unsigned u = __float_as_uint(f);
  u += 0x7FFF + ((u >> 16) & 1);  // round-to-nearest-even
  return (unsigned short)(u >> 16);
}

// ---------------------------------------------------------------- in_proj
__global__ __launch_bounds__(256) void k_inproj(const float* __restrict__ x,
                                                const float* __restrict__ Wp,
                                                float* __restrict__ xx,
                                                float* __restrict__ z1T) {
  const int b = blockIdx.z;
  const int m0 = blockIdx.y * 64;   // 0..704
  const int n0 = blockIdx.x * 64;   // l tile
  const int tid = threadIdx.x;
  const int lane = tid & 63, wv = tid >> 6;
  const int ln = lane & 15, qd = lane >> 4;
  __shared__ unsigned short Abf[64][40];  // [m][k] pad 40
  __shared__ unsigned short Bbf[64][40];  // [n][k] pad 40
  __shared__ float zt[64][68];
  f32x4 acc[4] = {};
  const float* xb = x + (size_t)b * 192 * L;
  for (int c0 = 0; c0 < 192; c0 += 32) {
    {  // stage A: 64m x 32k
      const int row = tid >> 2, kk = (tid & 3) * 8;
      float4 a0 = *(const float4*)&Wp[(size_t)(m0 + row) * 192 + c0 + kk];
      float4 a1 = *(const float4*)&Wp[(size_t)(m0 + row) * 192 + c0 + kk + 4];
      ushort8 v = {bf16r(a0.x), bf16r(a0.y), bf16r(a0.z), bf16r(a0.w),
                   bf16r(a1.x), bf16r(a1.y), bf16r(a1.z), bf16r(a1.w)};
      *(ushort8*)&Abf[row][kk] = v;
    }
    {  // stage B: X[k][n] -> Bbf[n][k] (transpose in staging)
      const int kr = tid >> 3, nc = tid & 7;
      const float* src = &xb[(size_t)(c0 + kr) * L + n0 + nc * 8];
      float4 b0 = *(const float4*)&src[0];
      float4 b1 = *(const float4*)&src[4];
      Bbf[nc * 8 + 0][kr] = bf16r(b0.x);
      Bbf[nc * 8 + 1][kr] = bf16r(b0.y);
      Bbf[nc * 8 + 2][kr] = bf16r(b0.z);
      Bbf[nc * 8 + 3][kr] = bf16r(b0.w);
      Bbf[nc * 8 + 4][kr] = bf16r(b1.x);
      Bbf[nc * 8 + 5][kr] = bf16r(b1.y);
      Bbf[nc * 8 + 6][kr] = bf16r(b1.z);
      Bbf[nc * 8 + 7][kr] = bf16r(b1.w);
    }
    __syncthreads();
    short8 af = *(short8*)&Abf[16 * wv + ln][8 * qd];
#pragma unroll
    for (int j = 0; j < 4; ++j) {
      short8 bf = *(short8*)&Bbf[16 * j + ln][8 * qd];
      acc[j] = __builtin_amdgcn_mfma_f32_16x16x32_bf16(af, bf, acc[j], 0, 0, 0);
    }
    __syncthreads();
  }
  if (m0 < 384) {
    float* xxb = xx + ((size_t)b * 384 + m0 + 16 * wv + 4 * qd) * L + n0 + ln;
#pragma unroll
    for (int j = 0; j < 4; ++j)
#pragma unroll
      for (int r = 0; r < 4; ++r) xxb[(size_t)r * L + 16 * j] = acc[j][r];
  } else {
#pragma unroll
    for (int j = 0; j < 4; ++j)
#pragma unroll
      for (int r = 0; r < 4; ++r)
        zt[16 * j + ln][16 * wv + 4 * qd + r] = gelu_f(acc[j][r]);
    __syncthreads();
    const int r = tid >> 2, cb = (tid & 3) * 16;
#pragma unroll
    for (int q = 0; q < 4; ++q) {
      int c = cb + q * 4;
      float4 v = make_float4(zt[r][c], zt[r][c + 1], zt[r][c + 2], zt[r][c + 3]);
      *(float4*)&z1T[((size_t)b * L + n0 + r) * 384 + (m0 - 384) + c] = v;
    }
  }
}

// ---------------------------------------------------------------- dw conv
__global__ __launch_bounds__(256) void k_conv(const float* __restrict__ xx,
                                              const float* __restrict__ conv_w,
                                              const float* __restrict__ conv_b,
                                              float* __restrict__ xc,
                                              float* __restrict__ xcT) {
  const int bid = blockIdx.x;
  const int d = bid % 384, b = bid / 384;
  const int tid = threadIdx.x;
  __shared__ float ls[48 * 49];
  __shared__ float xg[48 * 49];
  const float* src = xx + ((size_t)b * 384 + d) * L;
  for (int i = tid; i < L; i += 256) ls[(i / 48) * 49 + (i % 48)] = src[i];
  float cw[9];
  const float* cwp = conv_w + (size_t)d * 9;
#pragma unroll
  for (int r = 0; r < 9; ++r) cw[r] = cwp[r];
  const float cb = conv_b[d];
  __syncthreads();
  float* dst = xc + ((size_t)b * 384 + d) * L;
  for (int p = tid; p < L; p += 256) {
    int h = p / 48, w = p % 48;
    float acc = cb;
#pragma unroll
    for (int dy = -1; dy <= 1; ++dy) {
      int hh = h + dy;
      if (hh < 0 || hh >= 48) continue;
#pragma unroll
      for (int dx = -1; dx <= 1; ++dx) {
        int ww = w + dx;
        if (ww < 0 || ww >= 48) continue;
        acc = fmaf(ls[hh * 49 + ww], cw[(dy + 1) * 3 + (dx + 1)], acc);
      }
    }
    float g = gelu_f(acc);
    dst[p] = g;
    xg[h * 49 + w] = g;
  }
  __syncthreads();
  float* dstT = xcT + ((size_t)b * 384 + d) * L;
  for (int j = tid; j < L; j += 256) {
    int h = j % 48, w = j / 48;
    dstT[j] = xg[h * 49 + w];
  }
}

// ---------------------------------------------------------------- x_proj
__global__ __launch_bounds__(256) void k_xdbl(const float* __restrict__ xc,
                                              const float* __restrict__ xcT,
                                              const float* __restrict__ xpw,
                                              float* __restrict__ xdbl) {
  const int n0 = blockIdx.x * 64;
  const int bk = blockIdx.y;
  const int b = bk >> 2, k = bk & 3;
  const int tid = threadIdx.x;
  const int lane = tid & 63, wv = tid >> 6;
  const int ln = lane & 15, qd = lane >> 4;
  __shared__ unsigned short Abf[64][40];  // [m][k]
  __shared__ unsigned short Bbf[64][40];  // [n=l][k]
  f32x4 acc[4] = {};
  const float* src = ((k & 1) ? xcT : xc) + (size_t)b * 384 * L;
  const bool rev = (k >= 2);
  const float* ap = xpw + (size_t)k * 44 * 384;
  for (int c0 = 0; c0 < 384; c0 += 32) {
    {  // stage A (44 real rows; zero-fill 44..63)
      const int row = tid >> 2, kk = (tid & 3) * 8;
      ushort8 v = {0, 0, 0, 0, 0, 0, 0, 0};
      if (row < 44) {
        float4 a0 = *(const float4*)&ap[(size_t)row * 384 + c0 + kk];
        float4 a1 = *(const float4*)&ap[(size_t)row * 384 + c0 + kk + 4];
        v = ushort8{bf16r(a0.x), bf16r(a0.y), bf16r(a0.z), bf16r(a0.w),
                    bf16r(a1.x), bf16r(a1.y), bf16r(a1.z), bf16r(a1.w)};
      }
      *(ushort8*)&Abf[row][kk] = v;
    }
    {  // stage B with direction handling
      const int kr = tid >> 3, nc = tid & 7;
      const float* sr = src + (size_t)(c0 + kr) * L;
      const int base = n0 + nc * 8;
      float vals[8];
      if (!rev) {
        float4 f0 = *(const float4*)&sr[base];
        float4 f1 = *(const float4*)&sr[base + 4];
        vals[0] = f0.x; vals[1] = f0.y; vals[2] = f0.z; vals[3] = f0.w;
        vals[4] = f1.x; vals[5] = f1.y; vals[6] = f1.z; vals[7] = f1.w;
      } else {
        float4 f0 = *(const float4*)&sr[2300 - base];
        float4 f1 = *(const float4*)&sr[2296 - base];
        vals[0] = f0.w; vals[1] = f0.z; vals[2] = f0.y; vals[3] = f0.x;
        vals[4] = f1.w; vals[5] = f1.z; vals[6] = f1.y; vals[7] = f1.x;
      }
      Bbf[nc * 8 + 0][kr] = bf16r(vals[0]);
      Bbf[nc * 8 + 1][kr] = bf16r(vals[1]);
      Bbf[nc * 8 + 2][kr] = bf16r(vals[2]);
      Bbf[nc * 8 + 3][kr] = bf16r(vals[3]);
      Bbf[nc * 8 + 4][kr] = bf16r(vals[4]);
      Bbf[nc * 8 + 5][kr] = bf16r(vals[5]);
      Bbf[nc * 8 + 6][kr] = bf16r(vals[6]);
      Bbf[nc * 8 + 7][kr] = bf16r(vals[7]);
    }
    __syncthreads();
    short8 af = *(short8*)&Abf[16 * wv + ln][8 * qd];
#pragma unroll
    for (int j = 0; j < 4; ++j) {
      short8 bf = *(short8*)&Bbf[16 * j + ln][8 * qd];
      acc[j] = __builtin_amdgcn_mfma_f32_16x16x32_bf16(af, bf, acc[j], 0, 0, 0);
    }
    __syncthreads();
  }
  const int mbase = 16 * wv + 4 * qd;
  float* ob = xdbl + ((size_t)bk * 48 + mbase) * L + n0 + ln;
#pragma unroll
  for (int r = 0; r < 4; ++r) {
    if (mbase + r < 44) {
#pragma unroll
      for (int j = 0; j < 4; ++j) ob[(size_t)r * L + 16 * j] = acc[j][r];
    }
  }
}

// ---------------------------------------------------------------- transpose
__global__ __launch_bounds__(256) void k_transp(const float* __restrict__ xc,
                                                float* __restrict__ uT) {
  const int l0 = blockIdx.x * 64;
  const int d0 = blockIdx.y * 64;
  const int b = blockIdx.z;
  const int tid = threadIdx.x;
  __shared__ float ls[64][65];
  const float* src = xc + (size_t)b * 384 * L;
#pragma unroll
  for (int p = 0; p < 16; ++p) {
    int i = tid + p * 256;
    int row = i >> 6, col = i & 63;
    ls[row][col] = src[(size_t)(d0 + row) * L + l0 + col];
  }
  __syncthreads();
  float* dst = uT + (size_t)b * L * 384;
#pragma unroll
  for (int p = 0; p < 16; ++p) {
    int i = tid + p * 256;
    int lrow = i >> 6, dcol = i & 63;
    dst[(size_t)(l0 + lrow) * 384 + d0 + dcol] = ls[dcol][lrow];
  }
}

// ---------------------------------------------------------------- scan
// Pair-split, 12 chunks of 192 own + 128 warm, 32-step windows, dds packed
// bf16x2 (LDS 24KB), raw hw transcendentals, launch_bounds(256,4).
__global__ __launch_bounds__(256, 4) void k_scan(const float* __restrict__ xc,
                                                 const float* __restrict__ xcT,
                                                 const float* __restrict__ xdbl,
                                                 const float* __restrict__ dt_w,
                                                 const float* __restrict__ dt_b,
                                                 const float* __restrict__ A_logs,
                                                 float* __restrict__ ys) {
  const int bid = blockIdx.x;
  const int dth = bid % 3;
  const int c = (bid / 3) % 12;
  const int k = (bid / 36) % 4;
  const int b = bid / 144;
  const int tid = threadIdx.x;
  const int dloc = tid >> 1;
  const int nh = tid & 1;
  const int d = dth * 128 + dloc;
  const int kd = k * 384 + d;
  const bool rev = (k >= 2);

  float a2[8], h[8];
#pragma unroll
  for (int n = 0; n < 8; ++n) {
    a2[n] = -__builtin_amdgcn_exp2f(A_logs[(size_t)kd * 16 + 8 * nh + n] *
                                    1.44269504088896f) *
            1.44269504088896f;
    h[n] = 0.0f;
  }
  float dtw[12];
#pragma unroll
  for (int r = 0; r < 12; ++r) dtw[r] = dt_w[(size_t)kd * 12 + r];
  const float dtb = dt_b[kd];
  const float* xd = xdbl + (size_t)(b * 4 + k) * 48 * L;
  const float* urow = ((k & 1) ? xcT : xc) + ((size_t)b * 384 + d) * L;
  float* ysb = ys + (size_t)(b * 4 + k) * L * 384 + d;

  __shared__ __align__(16) float dtrT[32][20];
  __shared__ __align__(16) float BT[32][20];
  __shared__ __align__(16) float CT[32][20];
  __shared__ unsigned int dds[32][132];  // packed bf16(sp) | bf16(sp*u)<<16

  const int t_own = c * 192;
  const int t_first = (c == 0) ? 0 : t_own - 128;
  const int nwin = (c == 0) ? 6 : 10;

  for (int w = 0; w < nwin; ++w) {
    const int t0 = t_first + w * 32;
    __syncthreads();
#pragma unroll
    for (int it = 0; it < 6; ++it) {
      int idx = tid + it * 256;
      if (idx < 1408) {
        int r = idx >> 5, t = idx & 31;
        float v = xd[(size_t)r * L + t0 + t];
        if (r < 12) dtrT[t][r] = v;
        else if (r < 28) BT[t][r - 12] = v;
        else CT[t][r - 28] = v;
      }
    }
    __syncthreads();
    {
      const int tl0 = nh * 16;
#pragma unroll
      for (int q = 0; q < 4; ++q) {
        const int tg = t0 + tl0 + 4 * q;
        float4 u4;
        if (!rev) {
          u4 = *(const float4*)&urow[tg];
        } else {
          float4 tmp = *(const float4*)&urow[2300 - tg];
          u4 = make_float4(tmp.w, tmp.z, tmp.y, tmp.x);
        }
        float uv[4] = {u4.x, u4.y, u4.z, u4.w};
#pragma unroll
        for (int j = 0; j < 4; ++j) {
          const int tl = tl0 + 4 * q + j;
          float4 r0 = *(const float4*)&dtrT[tl][0];
          float4 r1 = *(const float4*)&dtrT[tl][4];
          float4 r2 = *(const float4*)&dtrT[tl][8];
          float raw = dtb;
          raw = fmaf(dtw[0], r0.x, raw);
          raw = fmaf(dtw[1], r0.y, raw);
          raw = fmaf(dtw[2], r0.z, raw);
          raw = fmaf(dtw[3], r0.w, raw);
          raw = fmaf(dtw[4], r1.x, raw);
          raw = fmaf(dtw[5], r1.y, raw);
          raw = fmaf(dtw[6], r1.z, raw);
          raw = fmaf(dtw[7], r1.w, raw);
          raw = fmaf(dtw[8], r2.x, raw);
          raw = fmaf(dtw[9], r2.y, raw);
          raw = fmaf(dtw[10], r2.z, raw);
          raw = fmaf(dtw[11], r2.w, raw);
          float E = __builtin_amdgcn_exp2f(raw * 1.44269504088896f);
          float sp = (raw > 20.0f)
                         ? raw
                         : 0.69314718055994531f * __builtin_amdgcn_logf(1.0f + E);
          float spu = sp * uv[j];
          dds[tl][dloc] =
              (unsigned)bf16r(sp) | ((unsigned)bf16r(spu) << 16);
        }
      }
    }
    __syncthreads();
    if (t0 >= t_own) {
#pragma unroll 4
      for (int s = 0; s < 32; ++s) {
        unsigned pk = dds[s][dloc];
        float px = __uint_as_float(pk << 16);          // sp
        float py = __uint_as_float(pk & 0xFFFF0000u);  // sp*u
        float4 B0 = *(const float4*)&BT[s][8 * nh];
        float4 B1 = *(const float4*)&BT[s][8 * nh + 4];
        float4 C0 = *(const float4*)&CT[s][8 * nh];
        float4 C1 = *(const float4*)&CT[s][8 * nh + 4];
        float e0 = __builtin_amdgcn_exp2f(px * a2[0]);
        float e1 = __builtin_amdgcn_exp2f(px * a2[1]);
        float e2 = __builtin_amdgcn_exp2f(px * a2[2]);
        float e3 = __builtin_amdgcn_exp2f(px * a2[3]);
        float e4 = __builtin_amdgcn_exp2f(px * a2[4]);
        float e5 = __builtin_amdgcn_exp2f(px * a2[5]);
        float e6 = __builtin_amdgcn_exp2f(px * a2[6]);
        float e7 = __builtin_amdgcn_exp2f(px * a2[7]);
        h[0] = fmaf(h[0], e0, py * B0.x);
        h[1] = fmaf(h[1], e1, py * B0.y);
        h[2] = fmaf(h[2], e2, py * B0.z);
        h[3] = fmaf(h[3], e3, py * B0.w);
        h[4] = fmaf(h[4], e4, py * B1.x);
        h[5] = fmaf(h[5], e5, py * B1.y);
        h[6] = fmaf(h[6], e6, py * B1.z);
        h[7] = fmaf(h[7], e7, py * B1.w);
        float y = h[0] * C0.x;
        y = fmaf(h[1], C0.y, y);
        y = fmaf(h[2], C0.z, y);
        y = fmaf(h[3], C0.w, y);
        y = fmaf(h[4], C1.x, y);
        y = fmaf(h[5], C1.y, y);
        y = fmaf(h[6], C1.z, y);
        y = fmaf(h[7], C1.w, y);
        float yo = __int_as_float(__builtin_amdgcn_update_dpp(
            0, __float_as_int(y), 0xB1, 0xF, 0xF, true));
        y += yo;
        if (nh == 0) ysb[(size_t)(t0 + s) * 384] = y;
      }
    } else {
#pragma unroll 4
      for (int s = 0; s < 32; ++s) {
        unsigned pk = dds[s][dloc];
        float px = __uint_as_float(pk << 16);
        float py = __uint_as_float(pk & 0xFFFF0000u);
        float4 B0 = *(const float4*)&BT[s][8 * nh];
        float4 B1 = *(const float4*)&BT[s][8 * nh + 4];
        float e0 = __builtin_amdgcn_exp2f(px * a2[0]);
        float e1 = __builtin_amdgcn_exp2f(px * a2[1]);
        float e2 = __builtin_amdgcn_exp2f(px * a2[2]);
        float e3 = __builtin_amdgcn_exp2f(px * a2[3]);
        float e4 = __builtin_amdgcn_exp2f(px * a2[4]);
        float e5 = __builtin_amdgcn_exp2f(px * a2[5]);
        float e6 = __builtin_amdgcn_exp2f(px * a2[6]);
        float e7 = __builtin_amdgcn_exp2f(px * a2[7]);
        h[0] = fmaf(h[0], e0, py * B0.x);
        h[1] = fmaf(h[1], e1, py * B0.y);
        h[2] = fmaf(h[2], e2, py * B0.z);
        h[3] = fmaf(h[3], e3, py * B0.w);
        h[4] = fmaf(h[4], e4, py * B1.x);
        h[5] = fmaf(h[5], e5, py * B1.y);
        h[6] = fmaf(h[6], e6, py * B1.z);
        h[7] = fmaf(h[7], e7, py * B1.w);
      }
    }
  }
}

// ---------------------------------------------------------------- merge+LN
__global__ __launch_bounds__(384) void k_merge(const float* __restrict__ ys,
                                               const float* __restrict__ z1T,
                                               const float* __restrict__ uT,
                                               const float* __restrict__ Ds,
                                               const float* __restrict__ ln_w,
                                               const float* __restrict__ ln_b,
                                               float* __restrict__ yln) {
  const int b = blockIdx.x / L;
  const int l = blockIdx.x % L;
  const int d = threadIdx.x;
  const int hh = l / 48, ww = l % 48;
  const int j = ww * 48 + hh;
  const float sumD = Ds[d] + Ds[384 + d] + Ds[768 + d] + Ds[1152 + d];
  const float* base = ys + (size_t)b * 4 * L * 384;
  float v = base[(size_t)(0 * L + l) * 384 + d] +
            base[(size_t)(1 * L + j) * 384 + d] +
            base[(size_t)(2 * L + (2303 - l)) * 384 + d] +
            base[(size_t)(3 * L + (2303 - j)) * 384 + d];
  v = fmaf(uT[((size_t)b * L + l) * 384 + d], sumD, v);
  float s1 = v, s2 = v * v;
#pragma unroll
  for (int off = 32; off; off >>= 1) {
    s1 += __shfl_xor(s1, off);
    s2 += __shfl_xor(s2, off);
  }
  __shared__ float ps1[6], ps2[6];
  const int wv = threadIdx.x >> 6;
  if ((threadIdx.x & 63) == 0) { ps1[wv] = s1; ps2[wv] = s2; }
  __syncthreads();
  float t1 = 0.f, t2 = 0.f;
#pragma unroll
  for (int i = 0; i < 6; ++i) { t1 += ps1[i]; t2 += ps2[i]; }
  const float mu = t1 * (1.0f / 384.0f);
  const float var = t2 * (1.0f / 384.0f) - mu * mu;
  const float rs = rsqrtf(var + 1e-5f);
  const float yv = (v - mu) * rs * ln_w[d] + ln_b[d];
  yln[((size_t)b * L + l) * 384 + d] = yv * z1T[((size_t)b * L + l) * 384 + d];
}

// ---------------------------------------------------------------- out_proj
__global__ __launch_bounds__(256) void k_outproj(const float* __restrict__ yln,
                                                 const float* __restrict__ W2,
                                                 float* __restrict__ out) {
  const int n0 = blockIdx.x * 64;   // l tile
  const int m0 = blockIdx.y * 64;   // c tile (0..128)
  const int b = blockIdx.z;
  const int tid = threadIdx.x;
  const int lane = tid & 63, wv = tid >> 6;
  const int ln = lane & 15, qd = lane >> 4;
  __shared__ unsigned short Abf[64][40];  // [m][k]
  __shared__ unsigned short Bbf[64][40];  // [n][k]
  f32x4 acc[4] = {};
  const float* yb = yln + (size_t)b * L * 384;
  for (int k0 = 0; k0 < 384; k0 += 32) {
    const int row = tid >> 2, kk = (tid & 3) * 8;
    {
      float4 a0 = *(const float4*)&W2[(size_t)(m0 + row) * 384 + k0 + kk];
      float4 a1 = *(const float4*)&W2[(size_t)(m0 + row) * 384 + k0 + kk + 4];
      ushort8 v = {bf16r(a0.x), bf16r(a0.y), bf16r(a0.z), bf16r(a0.w),
                   bf16r(a1.x), bf16r(a1.y), bf16r(a1.z), bf16r(a1.w)};
      *(ushort8*)&Abf[row][kk] = v;
    }
    {
      float4 b0 = *(const float4*)&yb[(size_t)(n0 + row) * 384 + k0 + kk];
      float4 b1 = *(const float4*)&yb[(size_t)(n0 + row) * 384 + k0 + kk + 4];
      ushort8 v = {bf16r(b0.x), bf16r(b0.y), bf16r(b0.z), bf16r(b0.w),
                   bf16r(b1.x), bf16r(b1.y), bf16r(b1.z), bf16r(b1.w)};
      *(ushort8*)&Bbf[row][kk] = v;
    }
    __syncthreads();
    short8 af = *(short8*)&Abf[16 * wv + ln][8 * qd];
#pragma unroll
    for (int j = 0; j < 4; ++j) {
      short8 bf = *(short8*)&Bbf[16 * j + ln][8 * qd];
      acc[j] = __builtin_amdgcn_mfma_f32_16x16x32_bf16(af, bf, acc[j], 0, 0, 0);
    }
    __syncthreads();
  }
  float* ob = out + ((size_t)b * 192 + m0 + 16 * wv + 4 * qd) * L + n0 + ln;
#pragma unroll
  for (int j = 0; j < 4; ++j)
#pragma unroll
    for (int r = 0; r < 4; ++r) ob[(size_t)r * L + 16 * j] = acc[j][r];
}

// ---------------------------------------------------------------- launch
extern "C" void kernel_launch(void* const* d_in, const int* in_sizes, int n_in,
                              void* d_out, int out_size, void* d_ws, size_t ws_size,
                              hipStream_t stream) {
  const float* x = (const float*)d_in[0];
  const float* in_proj_w = (const float*)d_in[1];
  const float* conv_w = (const float*)d_in[2];
  const float* conv_b = (const float*)d_in[3];
  const float* x_proj_w = (const float*)d_in[4];
  const float* dt_w = (const float*)d_in[5];
  const float* dt_b = (const float*)d_in[6];
  const float* A_logs = (const float*)d_in[7];
  const float* Ds = (const float*)d_in[8];
  const float* ln_w = (const float*)d_in[9];
  const float* ln_b = (const float*)d_in[10];
  const float* out_proj_w = (const float*)d_in[11];
  float* out = (float*)d_out;
  float* ws = (float*)d_ws;

  const size_t SZ_BDL = (size_t)8 * 384 * L;  // 7,077,888
  float* xx = ws;                      // (B,384,L); reused as uT, then yln
  float* z1T = xx + SZ_BDL;            // (B,L,384)
  float* xconv = z1T + SZ_BDL;         // (B,384,L) hw
  float* xconvT = xconv + SZ_BDL;      // (B,384,L) wh
  float* xdbl = xconvT + SZ_BDL;       // (B,4,48,L)
  float* ys = xdbl + (size_t)8 * 4 * 48 * L;  // (B,4,L,384)
  float* uT = xx;                      // alias (xx dead after conv)
  float* yln = xx;                     // alias (per-thread RAW on same index)

  k_inproj<<<dim3(36, 12, 8), 256, 0, stream>>>(x, in_proj_w, xx, z1T);
  k_conv<<<dim3(3072), 256, 0, stream>>>(xx, conv_w, conv_b, xconv, xconvT);
  k_xdbl<<<dim3(36, 32), 256, 0, stream>>>(xconv, xconvT, x_proj_w, xdbl);
  k_transp<<<dim3(36, 6, 8), 256, 0, stream>>>(xconv, uT);
  k_scan<<<dim3(1152), 256, 0, stream>>>(xconv, xconvT, xdbl, dt_w, dt_b,
                                         A_logs, ys);
  k_merge<<<dim3(8 * L), 384, 0, stream>>>(ys, z1T, uT, Ds, ln_w, ln_b, yln);
  k_outproj<<<dim3(36, 3, 8), 256, 0, stream>>>(yln, out_proj_w, out);
}

// Round 20
// 368.686 us; speedup vs baseline: 1.1202x; 1.1202x over previous
//
#include <hip/hip_runtime.h>
#include <cstdint>

// SS2D forward. Round 20 = R15 verbatim (best measured: 369us).
// R19 (bf16-packed dds, 12 chunks) regressed to 413: occupancy stayed
// pinned at ~28% regardless of LDS/grid caps — the barrier-phase structure
// sets residency, so added work/unpack cost was pure loss. R15 is the
// empirical optimum across all tried axes (states/thread, window, chunks,
// LDS size, dds dtype, launch bounds).
// B=8 C=192 H=W=48 L=2304 D_EXP=D_INNER=384 K=4 N=16 R=12

static constexpr int L = 2304;

typedef __attribute__((ext_vector_type(8))) short short8;
typedef __attribute__((ext_vector_type(8))) unsigned short ushort8;
typedef __attribute__((ext_vector_type(4))) float f32x4;

__device__ __forceinline__ float gelu_f(float x) {
  return 0.5f * x * (1.0f + erff(x * 0.70710678118654752440f));
}

__device__ __forceinline__ unsigned short bf16r(float f) {
  unsigned u = __float_as_uint(f);
  u += 0x7FFF + ((u >> 16) & 1);  // round-to-nearest-even
  return (unsigned short)(u >> 16);
}

// ---------------------------------------------------------------- in_proj
__global__ __launch_bounds__(256) void k_inproj(const float* __restrict__ x,
                                                const float* __restrict__ Wp,
                                                float* __restrict__ xx,
                                                float* __restrict__ z1T) {
  const int b = blockIdx.z;
  const int m0 = blockIdx.y * 64;   // 0..704
  const int n0 = blockIdx.x * 64;   // l tile
  const int tid = threadIdx.x;
  const int lane = tid & 63, wv = tid >> 6;
  const int ln = lane & 15, qd = lane >> 4;
  __shared__ unsigned short Abf[64][40];  // [m][k] pad 40
  __shared__ unsigned short Bbf[64][40];  // [n][k] pad 40
  __shared__ float zt[64][68];
  f32x4 acc[4] = {};
  const float* xb = x + (size_t)b * 192 * L;
  for (int c0 = 0; c0 < 192; c0 += 32) {
    {  // stage A: 64m x 32k
      const int row = tid >> 2, kk = (tid & 3) * 8;
      float4 a0 = *(const float4*)&Wp[(size_t)(m0 + row) * 192 + c0 + kk];
      float4 a1 = *(const float4*)&Wp[(size_t)(m0 + row) * 192 + c0 + kk + 4];
      ushort8 v = {bf16r(a0.x), bf16r(a0.y), bf16r(a0.z), bf16r(a0.w),
                   bf16r(a1.x), bf16r(a1.y), bf16r(a1.z), bf16r(a1.w)};
      *(ushort8*)&Abf[row][kk] = v;
    }
    {  // stage B: X[k][n] -> Bbf[n][k] (transpose in staging)
      const int kr = tid >> 3, nc = tid & 7;
      const float* src = &xb[(size_t)(c0 + kr) * L + n0 + nc * 8];
      float4 b0 = *(const float4*)&src[0];
      float4 b1 = *(const float4*)&src[4];
      Bbf[nc * 8 + 0][kr] = bf16r(b0.x);
      Bbf[nc * 8 + 1][kr] = bf16r(b0.y);
      Bbf[nc * 8 + 2][kr] = bf16r(b0.z);
      Bbf[nc * 8 + 3][kr] = bf16r(b0.w);
      Bbf[nc * 8 + 4][kr] = bf16r(b1.x);
      Bbf[nc * 8 + 5][kr] = bf16r(b1.y);
      Bbf[nc * 8 + 6][kr] = bf16r(b1.z);
      Bbf[nc * 8 + 7][kr] = bf16r(b1.w);
    }
    __syncthreads();
    short8 af = *(short8*)&Abf[16 * wv + ln][8 * qd];
#pragma unroll
    for (int j = 0; j < 4; ++j) {
      short8 bf = *(short8*)&Bbf[16 * j + ln][8 * qd];
      acc[j] = __builtin_amdgcn_mfma_f32_16x16x32_bf16(af, bf, acc[j], 0, 0, 0);
    }
    __syncthreads();
  }
  if (m0 < 384) {
    float* xxb = xx + ((size_t)b * 384 + m0 + 16 * wv + 4 * qd) * L + n0 + ln;
#pragma unroll
    for (int j = 0; j < 4; ++j)
#pragma unroll
      for (int r = 0; r < 4; ++r) xxb[(size_t)r * L + 16 * j] = acc[j][r];
  } else {
#pragma unroll
    for (int j = 0; j < 4; ++j)
#pragma unroll
      for (int r = 0; r < 4; ++r)
        zt[16 * j + ln][16 * wv + 4 * qd + r] = gelu_f(acc[j][r]);
    __syncthreads();
    const int r = tid >> 2, cb = (tid & 3) * 16;
#pragma unroll
    for (int q = 0; q < 4; ++q) {
      int c = cb + q * 4;
      float4 v = make_float4(zt[r][c], zt[r][c + 1], zt[r][c + 2], zt[r][c + 3]);
      *(float4*)&z1T[((size_t)b * L + n0 + r) * 384 + (m0 - 384) + c] = v;
    }
  }
}

// ---------------------------------------------------------------- dw conv
__global__ __launch_bounds__(256) void k_conv(const float* __restrict__ xx,
                                              const float* __restrict__ conv_w,
                                              const float* __restrict__ conv_b,
                                              float* __restrict__ xc,
                                              float* __restrict__ xcT) {
  const int bid = blockIdx.x;
  const int d = bid % 384, b = bid / 384;
  const int tid = threadIdx.x;
  __shared__ float ls[48 * 49];
  __shared__ float xg[48 * 49];
  const float* src = xx + ((size_t)b * 384 + d) * L;
  for (int i = tid; i < L; i += 256) ls[(i / 48) * 49 + (i % 48)] = src[i];
  float cw[9];
  const float* cwp = conv_w + (size_t)d * 9;
#pragma unroll
  for (int r = 0; r < 9; ++r) cw[r] = cwp[r];
  const float cb = conv_b[d];
  __syncthreads();
  float* dst = xc + ((size_t)b * 384 + d) * L;
  for (int p = tid; p < L; p += 256) {
    int h = p / 48, w = p % 48;
    float acc = cb;
#pragma unroll
    for (int dy = -1; dy <= 1; ++dy) {
      int hh = h + dy;
      if (hh < 0 || hh >= 48) continue;
#pragma unroll
      for (int dx = -1; dx <= 1; ++dx) {
        int ww = w + dx;
        if (ww < 0 || ww >= 48) continue;
        acc = fmaf(ls[hh * 49 + ww], cw[(dy + 1) * 3 + (dx + 1)], acc);
      }
    }
    float g = gelu_f(acc);
    dst[p] = g;
    xg[h * 49 + w] = g;
  }
  __syncthreads();
  float* dstT = xcT + ((size_t)b * 384 + d) * L;
  for (int j = tid; j < L; j += 256) {
    int h = j % 48, w = j / 48;
    dstT[j] = xg[h * 49 + w];
  }
}

// ---------------------------------------------------------------- x_proj
__global__ __launch_bounds__(256) void k_xdbl(const float* __restrict__ xc,
                                              const float* __restrict__ xcT,
                                              const float* __restrict__ xpw,
                                              float* __restrict__ xdbl) {
  const int n0 = blockIdx.x * 64;
  const int bk = blockIdx.y;
  const int b = bk >> 2, k = bk & 3;
  const int tid = threadIdx.x;
  const int tx = tid & 15, ty = tid >> 4;
  __shared__ __align__(16) float As[16][64];
  __shared__ __align__(16) float Bs[16][64];
  float acc[4][4] = {};
  const float* src = ((k & 1) ? xcT : xc) + (size_t)b * 384 * L;
  const bool rev = (k >= 2);
  const float* ap = xpw + (size_t)k * 44 * 384;
  for (int c0 = 0; c0 < 384; c0 += 16) {
    {
      const int mm = tid & 63, kq = tid >> 6;
      float4 a = make_float4(0.f, 0.f, 0.f, 0.f);
      if (mm < 44) a = *(const float4*)&ap[(size_t)mm * 384 + c0 + kq * 4];
      As[kq * 4 + 0][mm] = a.x; As[kq * 4 + 1][mm] = a.y;
      As[kq * 4 + 2][mm] = a.z; As[kq * 4 + 3][mm] = a.w;
    }
    {
      const int n4 = (tid & 15) * 4, kk = tid >> 4;
      const float* sr = src + (size_t)(c0 + kk) * L;
      float4 v;
      if (!rev) {
        v = *(const float4*)&sr[n0 + n4];
      } else {
        float4 t = *(const float4*)&sr[2300 - n0 - n4];
        v = make_float4(t.w, t.z, t.y, t.x);
      }
      *(float4*)&Bs[kk][n4] = v;
    }
    __syncthreads();
#pragma unroll
    for (int kk = 0; kk < 16; ++kk) {
      float4 a4 = *(const float4*)&As[kk][ty * 4];
      float4 b4 = *(const float4*)&Bs[kk][tx * 4];
      float av[4] = {a4.x, a4.y, a4.z, a4.w};
      float bv[4] = {b4.x, b4.y, b4.z, b4.w};
#pragma unroll
      for (int i = 0; i < 4; ++i)
#pragma unroll
        for (int j = 0; j < 4; ++j) acc[i][j] = fmaf(av[i], bv[j], acc[i][j]);
    }
    __syncthreads();
  }
#pragma unroll
  for (int i = 0; i < 4; ++i) {
    int m = ty * 4 + i;
    if (m < 44) {
      float4 v = make_float4(acc[i][0], acc[i][1], acc[i][2], acc[i][3]);
      *(float4*)&xdbl[((size_t)bk * 48 + m) * L + n0 + tx * 4] = v;
    }
  }
}

// ---------------------------------------------------------------- transpose
__global__ __launch_bounds__(256) void k_transp(const float* __restrict__ xc,
                                                float* __restrict__ uT) {
  const int l0 = blockIdx.x * 64;
  const int d0 = blockIdx.y * 64;
  const int b = blockIdx.z;
  const int tid = threadIdx.x;
  __shared__ float ls[64][65];
  const float* src = xc + (size_t)b * 384 * L;
#pragma unroll
  for (int p = 0; p < 16; ++p) {
    int i = tid + p * 256;
    int row = i >> 6, col = i & 63;
    ls[row][col] = src[(size_t)(d0 + row) * L + l0 + col];
  }
  __syncthreads();
  float* dst = uT + (size_t)b * L * 384;
#pragma unroll
  for (int p = 0; p < 16; ++p) {
    int i = tid + p * 256;
    int lrow = i >> 6, dcol = i & 63;
    dst[(size_t)(l0 + lrow) * 384 + d0 + dcol] = ls[dcol][lrow];
  }
}

// ---------------------------------------------------------------- scan
// Pair-split (d = tid>>1, nh = tid&1, 8 states/thread), 9 chunks of 256 own
// + 128 warm, 32-step windows, cooperative delta phase into dds. All
// transcendentals = raw hw builtins (v_exp_f32 / v_log_f32, no libm fixup).
__global__ __launch_bounds__(256, 4) void k_scan(const float* __restrict__ xc,
                                                 const float* __restrict__ xcT,
                                                 const float* __restrict__ xdbl,
                                                 const float* __restrict__ dt_w,
                                                 const float* __restrict__ dt_b,
                                                 const float* __restrict__ A_logs,
                                                 float* __restrict__ ys) {
  const int bid = blockIdx.x;
  const int dth = bid % 3;
  const int c = (bid / 3) % 9;
  const int k = (bid / 27) % 4;
  const int b = bid / 108;
  const int tid = threadIdx.x;
  const int dloc = tid >> 1;
  const int nh = tid & 1;
  const int d = dth * 128 + dloc;
  const int kd = k * 384 + d;
  const bool rev = (k >= 2);

  float a2[8], h[8];
#pragma unroll
  for (int n = 0; n < 8; ++n) {
    a2[n] = -__builtin_amdgcn_exp2f(A_logs[(size_t)kd * 16 + 8 * nh + n] *
                                    1.44269504088896f) *
            1.44269504088896f;
    h[n] = 0.0f;
  }
  float dtw[12];
#pragma unroll
  for (int r = 0; r < 12; ++r) dtw[r] = dt_w[(size_t)kd * 12 + r];
  const float dtb = dt_b[kd];
  const float* xd = xdbl + (size_t)(b * 4 + k) * 48 * L;
  const float* urow = ((k & 1) ? xcT : xc) + ((size_t)b * 384 + d) * L;
  float* ysb = ys + (size_t)(b * 4 + k) * L * 384 + d;

  __shared__ __align__(16) float dtrT[32][20];
  __shared__ __align__(16) float BT[32][20];
  __shared__ __align__(16) float CT[32][20];
  __shared__ __align__(16) float dds[32][258];

  const int t_own = c * 256;
  const int t_first = (c == 0) ? 0 : t_own - 128;
  const int nwin = (c == 0) ? 8 : 12;

  for (int w = 0; w < nwin; ++w) {
    const int t0 = t_first + w * 32;
    __syncthreads();
#pragma unroll
    for (int it = 0; it < 6; ++it) {
      int idx = tid + it * 256;
      if (idx < 1408) {
        int r = idx >> 5, t = idx & 31;
        float v = xd[(size_t)r * L + t0 + t];
        if (r < 12) dtrT[t][r] = v;
        else if (r < 28) BT[t][r - 12] = v;
        else CT[t][r - 28] = v;
      }
    }
    __syncthreads();
    {
      const int tl0 = nh * 16;
#pragma unroll
      for (int q = 0; q < 4; ++q) {
        const int tg = t0 + tl0 + 4 * q;
        float4 u4;
        if (!rev) {
          u4 = *(const float4*)&urow[tg];
        } else {
          float4 tmp = *(const float4*)&urow[2300 - tg];
          u4 = make_float4(tmp.w, tmp.z, tmp.y, tmp.x);
        }
        float uv[4] = {u4.x, u4.y, u4.z, u4.w};
#pragma unroll
        for (int j = 0; j < 4; ++j) {
          const int tl = tl0 + 4 * q + j;
          float4 r0 = *(const float4*)&dtrT[tl][0];
          float4 r1 = *(const float4*)&dtrT[tl][4];
          float4 r2 = *(const float4*)&dtrT[tl][8];
          float raw = dtb;
          raw = fmaf(dtw[0], r0.x, raw);
          raw = fmaf(dtw[1], r0.y, raw);
          raw = fmaf(dtw[2], r0.z, raw);
          raw = fmaf(dtw[3], r0.w, raw);
          raw = fmaf(dtw[4], r1.x, raw);
          raw = fmaf(dtw[5], r1.y, raw);
          raw = fmaf(dtw[6], r1.z, raw);
          raw = fmaf(dtw[7], r1.w, raw);
          raw = fmaf(dtw[8], r2.x, raw);
          raw = fmaf(dtw[9], r2.y, raw);
          raw = fmaf(dtw[10], r2.z, raw);
          raw = fmaf(dtw[11], r2.w, raw);
          // softplus via raw hw exp2/log2 (flush-to-zero is correct limit)
          float E = __builtin_amdgcn_exp2f(raw * 1.44269504088896f);
          float sp = (raw > 20.0f)
                         ? raw
                         : 0.69314718055994531f * __builtin_amdgcn_logf(1.0f + E);
          *(float2*)&dds[tl][2 * dloc] = make_float2(sp, sp * uv[j]);
        }
      }
    }
    __syncthreads();
    if (t0 >= t_own) {
#pragma unroll 4
      for (int s = 0; s < 32; ++s) {
        float2 p = *(const float2*)&dds[s][2 * dloc];
        float4 B0 = *(const float4*)&BT[s][8 * nh];
        float4 B1 = *(const float4*)&BT[s][8 * nh + 4];
        float4 C0 = *(const float4*)&CT[s][8 * nh];
        float4 C1 = *(const float4*)&CT[s][8 * nh + 4];
        float e0 = __builtin_amdgcn_exp2f(p.x * a2[0]);
        float e1 = __builtin_amdgcn_exp2f(p.x * a2[1]);
        float e2 = __builtin_amdgcn_exp2f(p.x * a2[2]);
        float e3 = __builtin_amdgcn_exp2f(p.x * a2[3]);
        float e4 = __builtin_amdgcn_exp2f(p.x * a2[4]);
        float e5 = __builtin_amdgcn_exp2f(p.x * a2[5]);
        float e6 = __builtin_amdgcn_exp2f(p.x * a2[6]);
        float e7 = __builtin_amdgcn_exp2f(p.x * a2[7]);
        h[0] = fmaf(h[0], e0, p.y * B0.x);
        h[1] = fmaf(h[1], e1, p.y * B0.y);
        h[2] = fmaf(h[2], e2, p.y * B0.z);
        h[3] = fmaf(h[3], e3, p.y * B0.w);
        h[4] = fmaf(h[4], e4, p.y * B1.x);
        h[5] = fmaf(h[5], e5, p.y * B1.y);
        h[6] = fmaf(h[6], e6, p.y * B1.z);
        h[7] = fmaf(h[7], e7, p.y * B1.w);
        float y = h[0] * C0.x;
        y = fmaf(h[1], C0.y, y);
        y = fmaf(h[2], C0.z, y);
        y = fmaf(h[3], C0.w, y);
        y = fmaf(h[4], C1.x, y);
        y = fmaf(h[5], C1.y, y);
        y = fmaf(h[6], C1.z, y);
        y = fmaf(h[7], C1.w, y);
        float yo = __int_as_float(__builtin_amdgcn_update_dpp(
            0, __float_as_int(y), 0xB1, 0xF, 0xF, true));
        y += yo;
        if (nh == 0) ysb[(size_t)(t0 + s) * 384] = y;
      }
    } else {
#pragma unroll 4
      for (int s = 0; s < 32; ++s) {
        float2 p = *(const float2*)&dds[s][2 * dloc];
        float4 B0 = *(const float4*)&BT[s][8 * nh];
        float4 B1 = *(const float4*)&BT[s][8 * nh + 4];
        float e0 = __builtin_amdgcn_exp2f(p.x * a2[0]);
        float e1 = __builtin_amdgcn_exp2f(p.x * a2[1]);
        float e2 = __builtin_amdgcn_exp2f(p.x * a2[2]);
        float e3 = __builtin_amdgcn_exp2f(p.x * a2[3]);
        float e4 = __builtin_amdgcn_exp2f(p.x * a2[4]);
        float e5 = __builtin_amdgcn_exp2f(p.x * a2[5]);
        float e6 = __builtin_amdgcn_exp2f(p.x * a2[6]);
        float e7 = __builtin_amdgcn_exp2f(p.x * a2[7]);
        h[0] = fmaf(h[0], e0, p.y * B0.x);
        h[1] = fmaf(h[1], e1, p.y * B0.y);
        h[2] = fmaf(h[2], e2, p.y * B0.z);
        h[3] = fmaf(h[3], e3, p.y * B0.w);
        h[4] = fmaf(h[4], e4, p.y * B1.x);
        h[5] = fmaf(h[5], e5, p.y * B1.y);
        h[6] = fmaf(h[6], e6, p.y * B1.z);
        h[7] = fmaf(h[7], e7, p.y * B1.w);
      }
    }
  }
}

// ---------------------------------------------------------------- merge+LN
__global__ __launch_bounds__(384) void k_merge(const float* __restrict__ ys,
                                               const float* __restrict__ z1T,
                                               const float* __restrict__ uT,
                                               const float* __restrict__ Ds,
                                               const float* __restrict__ ln_w,
                                               const float* __restrict__ ln_b,
                                               float* __restrict__ yln) {
  const int b = blockIdx.x / L;
  const int l = blockIdx.x % L;
  const int d = threadIdx.x;
  const int hh = l / 48, ww = l % 48;
  const int j = ww * 48 + hh;
  const float sumD = Ds[d] + Ds[384 + d] + Ds[768 + d] + Ds[1152 + d];
  const float* base = ys + (size_t)b * 4 * L * 384;
  float v = base[(size_t)(0 * L + l) * 384 + d] +
            base[(size_t)(1 * L + j) * 384 + d] +
            base[(size_t)(2 * L + (2303 - l)) * 384 + d] +
            base[(size_t)(3 * L + (2303 - j)) * 384 + d];
  v = fmaf(uT[((size_t)b * L + l) * 384 + d], sumD, v);
  float s1 = v, s2 = v * v;
#pragma unroll
  for (int off = 32; off; off >>= 1) {
    s1 += __shfl_xor(s1, off);
    s2 += __shfl_xor(s2, off);
  }
  __shared__ float ps1[6], ps2[6];
  const int wv = threadIdx.x >> 6;
  if ((threadIdx.x & 63) == 0) { ps1[wv] = s1; ps2[wv] = s2; }
  __syncthreads();
  float t1 = 0.f, t2 = 0.f;
#pragma unroll
  for (int i = 0; i < 6; ++i) { t1 += ps1[i]; t2 += ps2[i]; }
  const float mu = t1 * (1.0f / 384.0f);
  const float var = t2 * (1.0f / 384.0f) - mu * mu;
  const float rs = rsqrtf(var + 1e-5f);
  const float yv = (v - mu) * rs * ln_w[d] + ln_b[d];
  yln[((size_t)b * L + l) * 384 + d] = yv * z1T[((size_t)b * L + l) * 384 + d];
}

// ---------------------------------------------------------------- out_proj
__global__ __launch_bounds__(256) void k_outproj(const float* __restrict__ yln,
                                                 const float* __restrict__ W2,
                                                 float* __restrict__ out) {
  const int n0 = blockIdx.x * 64;   // l tile
  const int m0 = blockIdx.y * 64;   // c tile (0..128)
  const int b = blockIdx.z;
  const int tid = threadIdx.x;
  const int lane = tid & 63, wv = tid >> 6;
  const int ln = lane & 15, qd = lane >> 4;
  __shared__ unsigned short Abf[64][40];  // [m][k]
  __shared__ unsigned short Bbf[64][40];  // [n][k]
  f32x4 acc[4] = {};
  const float* yb = yln + (size_t)b * L * 384;
  for (int k0 = 0; k0 < 384; k0 += 32) {
    const int row = tid >> 2, kk = (tid & 3) * 8;
    {
      float4 a0 = *(const float4*)&W2[(size_t)(m0 + row) * 384 + k0 + kk];
      float4 a1 = *(const float4*)&W2[(size_t)(m0 + row) * 384 + k0 + kk + 4];
      ushort8 v = {bf16r(a0.x), bf16r(a0.y), bf16r(a0.z), bf16r(a0.w),
                   bf16r(a1.x), bf16r(a1.y), bf16r(a1.z), bf16r(a1.w)};
      *(ushort8*)&Abf[row][kk] = v;
    }
    {
      float4 b0 = *(const float4*)&yb[(size_t)(n0 + row) * 384 + k0 + kk];
      float4 b1 = *(const float4*)&yb[(size_t)(n0 + row) * 384 + k0 + kk + 4];
      ushort8 v = {bf16r(b0.x), bf16r(b0.y), bf16r(b0.z), bf16r(b0.w),
                   bf16r(b1.x), bf16r(b1.y), bf16r(b1.z), bf16r(b1.w)};
      *(ushort8*)&Bbf[row][kk] = v;
    }
    __syncthreads();
    short8 af = *(short8*)&Abf[16 * wv + ln][8 * qd];
#pragma unroll
    for (int j = 0; j < 4; ++j) {
      short8 bf = *(short8*)&Bbf[16 * j + ln][8 * qd];
      acc[j] = __builtin_amdgcn_mfma_f32_16x16x32_bf16(af, bf, acc[j], 0, 0, 0);
    }
    __syncthreads();
  }
  float* ob = out + ((size_t)b * 192 + m0 + 16 * wv + 4 * qd) * L + n0 + ln;
#pragma unroll
  for (int j = 0; j < 4; ++j)
#pragma unroll
    for (int r = 0; r < 4; ++r) ob[(size_t)r * L + 16 * j] = acc[j][r];
}

// ---------------------------------------------------------------- launch
extern "C" void kernel_launch(void* const* d_in, const int* in_sizes, int n_in,
                              void* d_out, int out_size, void* d_ws, size_t ws_size,
                              hipStream_t stream) {
  const float* x = (const float*)d_in[0];
  const float* in_proj_w = (const float*)d_in[1];
  const float* conv_w = (const float*)d_in[2];
  const float* conv_b = (const float*)d_in[3];
  const float* x_proj_w = (const float*)d_in[4];
  const float* dt_w = (const float*)d_in[5];
  const float* dt_b = (const float*)d_in[6];
  const float* A_logs = (const float*)d_in[7];
  const float* Ds = (const float*)d_in[8];
  const float* ln_w = (const float*)d_in[9];
  const float* ln_b = (const float*)d_in[10];
  const float* out_proj_w = (const float*)d_in[11];
  float* out = (float*)d_out;
  float* ws = (float*)d_ws;

  const size_t SZ_BDL = (size_t)8 * 384 * L;  // 7,077,888
  float* xx = ws;                      // (B,384,L); reused as uT, then yln
  float* z1T = xx + SZ_BDL;            // (B,L,384)
  float* xconv = z1T + SZ_BDL;         // (B,384,L) hw
  float* xconvT = xconv + SZ_BDL;      // (B,384,L) wh
  float* xdbl = xconvT + SZ_BDL;       // (B,4,48,L)
  float* ys = xdbl + (size_t)8 * 4 * 48 * L;  // (B,4,L,384)
  float* uT = xx;                      // alias (xx dead after conv)
  float* yln = xx;                     // alias (per-thread RAW on same index)

  k_inproj<<<dim3(36, 12, 8), 256, 0, stream>>>(x, in_proj_w, xx, z1T);
  k_conv<<<dim3(3072), 256, 0, stream>>>(xx, conv_w, conv_b, xconv, xconvT);
  k_xdbl<<<dim3(36, 32), 256, 0, stream>>>(xconv, xconvT, x_proj_w, xdbl);
  k_transp<<<dim3(36, 6, 8), 256, 0, stream>>>(xconv, uT);
  k_scan<<<dim3(864), 256, 0, stream>>>(xconv, xconvT, xdbl, dt_w, dt_b,
                                        A_logs, ys);
  k_merge<<<dim3(8 * L), 384, 0, stream>>>(ys, z1T, uT, Ds, ln_w, ln_b, yln);
  k_outproj<<<dim3(36, 3, 8), 256, 0, stream>>>(yln, out_proj_w, out);
}